// Round 1
// baseline (17446.967 us; speedup 1.0000x reference)
//
#include <hip/hip_runtime.h>
#include <hip/hip_bf16.h>

#define NGROUP 8
#define NB     32
#define TLEN   2048
#define LLEN   128
#define TDIM   768
#define VDIM   1024
#define ADIM   1024
#define DH     128          // ADIM / NGROUP
#define TT     64           // T tile
#define NTILE  (TLEN / TT)  // 32
#define ESTR   66           // padded stride for E [128][66]

// LDS layout (bytes):
//   qT   ushort[128][128]   @0        32768   (qT[dd][l], bf16)
//   vvS  ushort[128][128]   @32768    32768   (vv[l][dim], bf16)
//   kT   ushort[128][64]    @65536    16384   (kT[dd][tt], bf16)
//   vtS  ushort[64][128]    @81920    16384   (vt[tt][dim], bf16)
//   E    float[128][66]     @98304    33792   (E[l][tt] = exp(S) or 0)  [overlaid: Xst float[16][130]]
//   scale_col float[64]     @132096   256
//   s_row     float[128]    @132352   512
#define SMEM_BYTES 132864

__device__ __forceinline__ unsigned short f2bf(float f) {
    unsigned int u = __float_as_uint(f);
    u = (u + 0x7fffu + ((u >> 16) & 1u)) >> 16;   // round-to-nearest-even
    return (unsigned short)u;
}
__device__ __forceinline__ float bfbits(unsigned short h) {
    return __uint_as_float(((unsigned int)h) << 16);
}
__device__ __forceinline__ void unpk(unsigned int u, float& lo, float& hi) {
    lo = __uint_as_float(u << 16);
    hi = __uint_as_float(u & 0xffff0000u);
}

extern "C" __global__ __launch_bounds__(256, 1)
void attn_fused(const float* __restrict__ videofea,  // [b][vd][T]
                const float* __restrict__ textfea,   // [b][L][td]
                const int*   __restrict__ mask,      // [b][T][L]
                const float* __restrict__ Wq,  const float* __restrict__ bq,
                const float* __restrict__ Wk,  const float* __restrict__ bk,
                const float* __restrict__ Wvv, const float* __restrict__ bvv,
                const float* __restrict__ Wvt, const float* __restrict__ bvt,
                float* __restrict__ out)             // out_v [32][1024][2048] ++ out_t [32][128][1024]
{
    extern __shared__ char smem[];
    unsigned short* qT  = (unsigned short*)(smem);
    unsigned short* vvS = (unsigned short*)(smem + 32768);
    unsigned short* kT  = (unsigned short*)(smem + 65536);
    unsigned short* vtS = (unsigned short*)(smem + 81920);
    float* E    = (float*)(smem + 98304);
    float* Xst  = (float*)(smem + 98304);   // overlay, used only before main loop
    float* scale_col = (float*)(smem + 132096);
    float* s_row     = (float*)(smem + 132352);

    const int tid = threadIdx.x;
    const int g = blockIdx.x, b = blockIdx.y;
    const int gd0 = g * DH;

    const float* Vb   = videofea + (size_t)b * VDIM * TLEN;
    const float* Xb   = textfea  + (size_t)b * LLEN * TDIM;
    const int*   Mb   = mask     + (size_t)b * TLEN * LLEN;
    float* outv = out;
    float* outt = out + (size_t)NB * ADIM * TLEN;

    // ================= Phase 0: q and vv projections (one-time) =================
    {
        const int tx = tid & 15, ty = tid >> 4;
        const int dim0 = tx * 8, l0 = ty * 8;
        for (int pass = 0; pass < 2; ++pass) {
            const float* W    = (pass == 0) ? Wq : Wvv;
            const float* bias = (pass == 0) ? bq : bvv;
            float acc[8][8];
            #pragma unroll
            for (int i = 0; i < 8; ++i)
                #pragma unroll
                for (int j = 0; j < 8; ++j) acc[i][j] = 0.f;

            for (int c0 = 0; c0 < TDIM; c0 += 16) {
                __syncthreads();  // protect Xst reuse
                #pragma unroll
                for (int r = 0; r < 8; ++r) {
                    int idx = r * 256 + tid;          // 0..2047
                    int l = idx >> 4, kk = idx & 15;
                    Xst[kk * 130 + l] = Xb[l * TDIM + c0 + kk];
                }
                __syncthreads();
                #pragma unroll 4
                for (int kk = 0; kk < 16; ++kk) {
                    const float4 w0 = *(const float4*)&W[(size_t)(c0 + kk) * ADIM + gd0 + dim0];
                    const float4 w1 = *(const float4*)&W[(size_t)(c0 + kk) * ADIM + gd0 + dim0 + 4];
                    float w8[8] = {w0.x, w0.y, w0.z, w0.w, w1.x, w1.y, w1.z, w1.w};
                    float x8[8];
                    #pragma unroll
                    for (int i = 0; i < 8; ++i) x8[i] = Xst[kk * 130 + l0 + i];
                    #pragma unroll
                    for (int i = 0; i < 8; ++i)
                        #pragma unroll
                        for (int j = 0; j < 8; ++j) acc[i][j] += x8[i] * w8[j];
                }
            }
            float b8[8];
            #pragma unroll
            for (int j = 0; j < 8; ++j) b8[j] = bias[gd0 + dim0 + j];
            if (pass == 0) {
                #pragma unroll
                for (int i = 0; i < 8; ++i)
                    #pragma unroll
                    for (int j = 0; j < 8; ++j)
                        qT[(dim0 + j) * LLEN + l0 + i] = f2bf(acc[i][j] + b8[j]);
            } else {
                #pragma unroll
                for (int i = 0; i < 8; ++i)
                    #pragma unroll
                    for (int j = 0; j < 8; ++j)
                        vvS[(l0 + i) * DH + dim0 + j] = f2bf(acc[i][j] + b8[j]);
            }
        }
    }
    if (tid < 128) s_row[tid] = 0.f;
    __syncthreads();

    // out_t accumulator: (tx -> dim0 8-wide, ty -> l0 8-wide)
    float acct[8][8];
    #pragma unroll
    for (int i = 0; i < 8; ++i)
        #pragma unroll
        for (int j = 0; j < 8; ++j) acct[i][j] = 0.f;

    // ================= main loop over T tiles =================
    for (int it = 0; it < NTILE; ++it) {
        const int t0 = it * TT;

        // ---- Phase A: k/vt projection for this tile ----
        {
            const int tx = tid & 15, ty = tid >> 4;  // tx->dim0(8), ty->tt0(4)
            const int dim0 = tx * 8, tt0 = ty * 4;
            float ak[4][8], av[4][8];
            #pragma unroll
            for (int i = 0; i < 4; ++i)
                #pragma unroll
                for (int j = 0; j < 8; ++j) { ak[i][j] = 0.f; av[i][j] = 0.f; }

            #pragma unroll 4
            for (int c = 0; c < VDIM; ++c) {
                const float4 v4  = *(const float4*)&Vb[(size_t)c * TLEN + t0 + tt0];
                const float4 k0  = *(const float4*)&Wk [(size_t)c * ADIM + gd0 + dim0];
                const float4 k1  = *(const float4*)&Wk [(size_t)c * ADIM + gd0 + dim0 + 4];
                const float4 t0f = *(const float4*)&Wvt[(size_t)c * ADIM + gd0 + dim0];
                const float4 t1f = *(const float4*)&Wvt[(size_t)c * ADIM + gd0 + dim0 + 4];
                float vv4[4] = {v4.x, v4.y, v4.z, v4.w};
                float k8[8]  = {k0.x, k0.y, k0.z, k0.w, k1.x, k1.y, k1.z, k1.w};
                float t8[8]  = {t0f.x, t0f.y, t0f.z, t0f.w, t1f.x, t1f.y, t1f.z, t1f.w};
                #pragma unroll
                for (int i = 0; i < 4; ++i)
                    #pragma unroll
                    for (int j = 0; j < 8; ++j) {
                        ak[i][j] += vv4[i] * k8[j];
                        av[i][j] += vv4[i] * t8[j];
                    }
            }
            #pragma unroll
            for (int j = 0; j < 8; ++j) {
                float bkj = bk[gd0 + dim0 + j], bvj = bvt[gd0 + dim0 + j];
                #pragma unroll
                for (int i = 0; i < 4; ++i) {
                    kT [(dim0 + j) * TT + tt0 + i] = f2bf(ak[i][j] + bkj);
                    vtS[(tt0 + i) * DH + dim0 + j] = f2bf(av[i][j] + bvj);
                }
            }
        }
        __syncthreads();

        // ---- Phase B: S = q·kT, mask, exp -> E ----
        {
            const int tx = tid & 7, ty = tid >> 3;   // tx->tt0(8), ty->l0(4)
            const int tt0 = tx * 8, l0 = ty * 4;
            float s[4][8];
            #pragma unroll
            for (int i = 0; i < 4; ++i)
                #pragma unroll
                for (int j = 0; j < 8; ++j) s[i][j] = 0.f;

            #pragma unroll 2
            for (int dd = 0; dd < DH; ++dd) {
                ushort4 qr = *(const ushort4*)&qT[dd * LLEN + l0];
                uint4   kr = *(const uint4*)&kT[dd * TT + tt0];
                float q4[4] = {bfbits(qr.x), bfbits(qr.y), bfbits(qr.z), bfbits(qr.w)};
                float k8[8];
                unpk(kr.x, k8[0], k8[1]); unpk(kr.y, k8[2], k8[3]);
                unpk(kr.z, k8[4], k8[5]); unpk(kr.w, k8[6], k8[7]);
                #pragma unroll
                for (int i = 0; i < 4; ++i)
                    #pragma unroll
                    for (int j = 0; j < 8; ++j) s[i][j] += q4[i] * k8[j];
            }
            #pragma unroll
            for (int j = 0; j < 8; ++j) {
                const int4 m4 = *(const int4*)&Mb[(size_t)(t0 + tt0 + j) * LLEN + l0];
                int mm[4] = {m4.x, m4.y, m4.z, m4.w};
                #pragma unroll
                for (int i = 0; i < 4; ++i) {
                    float e = (mm[i] == 0) ? 0.f : __expf(s[i][j]);
                    E[(l0 + i) * ESTR + tt0 + j] = e;
                }
            }
        }
        __syncthreads();

        // ---- Phase C: column sums (softmax over L) + row sum accumulation ----
        if (tid < 64) {
            float cs = 0.f;
            #pragma unroll 4
            for (int l = 0; l < LLEN; ++l) cs += E[l * ESTR + tid];
            scale_col[tid] = 1.0f / (32.0f * fmaxf(cs, 1e-30f));
        } else if (tid < 192) {
            const int l = tid - 64;
            float rs = 0.f;
            #pragma unroll 4
            for (int tt = 0; tt < TT; ++tt) rs += E[l * ESTR + tt];
            s_row[l] += rs;
        }
        __syncthreads();

        // ---- Phase D: out_v tile = (E^T · vv) * scale_col ----
        {
            const int tx = tid & 15, ty = tid >> 4;  // tx->tt0(4), ty->dim0(8)
            const int tt0 = tx * 4, dim0 = ty * 8;
            float acc[8][4];
            #pragma unroll
            for (int j = 0; j < 8; ++j)
                #pragma unroll
                for (int i = 0; i < 4; ++i) acc[j][i] = 0.f;

            #pragma unroll 2
            for (int l = 0; l < LLEN; ++l) {
                float e0 = E[l * ESTR + tt0],     e1 = E[l * ESTR + tt0 + 1];
                float e2 = E[l * ESTR + tt0 + 2], e3 = E[l * ESTR + tt0 + 3];
                uint4 vr = *(const uint4*)&vvS[l * DH + dim0];
                float v8[8];
                unpk(vr.x, v8[0], v8[1]); unpk(vr.y, v8[2], v8[3]);
                unpk(vr.z, v8[4], v8[5]); unpk(vr.w, v8[6], v8[7]);
                #pragma unroll
                for (int j = 0; j < 8; ++j) {
                    acc[j][0] += v8[j] * e0; acc[j][1] += v8[j] * e1;
                    acc[j][2] += v8[j] * e2; acc[j][3] += v8[j] * e3;
                }
            }
            float sc[4] = {scale_col[tt0], scale_col[tt0 + 1], scale_col[tt0 + 2], scale_col[tt0 + 3]};
            #pragma unroll
            for (int j = 0; j < 8; ++j) {
                float4 o = {acc[j][0] * sc[0], acc[j][1] * sc[1], acc[j][2] * sc[2], acc[j][3] * sc[3]};
                *(float4*)&outv[((size_t)b * ADIM + gd0 + dim0 + j) * TLEN + t0 + tt0] = o;
            }
        }

        // ---- Phase E: acct += E · vt  (read-only on LDS, no barrier before) ----
        {
            const int tx = tid & 15, ty = tid >> 4;  // tx->dim0(8), ty->l0(8)
            const int dim0 = tx * 8, l0 = ty * 8;
            #pragma unroll 2
            for (int tt = 0; tt < TT; ++tt) {
                float e8[8];
                #pragma unroll
                for (int i = 0; i < 8; ++i) e8[i] = E[(l0 + i) * ESTR + tt];
                uint4 vr = *(const uint4*)&vtS[tt * DH + dim0];
                float v8[8];
                unpk(vr.x, v8[0], v8[1]); unpk(vr.y, v8[2], v8[3]);
                unpk(vr.z, v8[4], v8[5]); unpk(vr.w, v8[6], v8[7]);
                #pragma unroll
                for (int i = 0; i < 8; ++i)
                    #pragma unroll
                    for (int j = 0; j < 8; ++j) acct[i][j] += e8[i] * v8[j];
            }
        }
        __syncthreads();  // protect kT/vtS/E before next tile's Phase A/B
    }

    // ================= epilogue: out_t = acct / (32 * s_row) =================
    {
        const int tx = tid & 15, ty = tid >> 4;
        const int dim0 = tx * 8, l0 = ty * 8;
        #pragma unroll
        for (int i = 0; i < 8; ++i) {
            float inv = 1.0f / (32.0f * fmaxf(s_row[l0 + i], 1e-30f));
            float4 o0 = {acct[i][0] * inv, acct[i][1] * inv, acct[i][2] * inv, acct[i][3] * inv};
            float4 o1 = {acct[i][4] * inv, acct[i][5] * inv, acct[i][6] * inv, acct[i][7] * inv};
            size_t base = (size_t)b * LLEN * ADIM + (size_t)(l0 + i) * ADIM + gd0 + dim0;
            *(float4*)&outt[base]     = o0;
            *(float4*)&outt[base + 4] = o1;
        }
    }
}

extern "C" void kernel_launch(void* const* d_in, const int* in_sizes, int n_in,
                              void* d_out, int out_size, void* d_ws, size_t ws_size,
                              hipStream_t stream) {
    const float* videofea = (const float*)d_in[0];
    const float* textfea  = (const float*)d_in[1];
    const int*   mask     = (const int*)d_in[2];
    const float* Wq  = (const float*)d_in[3];
    const float* bq  = (const float*)d_in[4];
    const float* Wk  = (const float*)d_in[5];
    const float* bk  = (const float*)d_in[6];
    const float* Wvv = (const float*)d_in[7];
    const float* bvv = (const float*)d_in[8];
    const float* Wvt = (const float*)d_in[9];
    const float* bvt = (const float*)d_in[10];
    float* out = (float*)d_out;

    hipFuncSetAttribute((const void*)attn_fused,
                        hipFuncAttributeMaxDynamicSharedMemorySize, SMEM_BYTES);
    dim3 grid(NGROUP, NB);
    attn_fused<<<grid, 256, SMEM_BYTES, stream>>>(
        videofea, textfea, mask, Wq, bq, Wk, bk, Wvv, bvv, Wvt, bvt, out);
}

// Round 2
// 15630.994 us; speedup vs baseline: 1.1162x; 1.1162x over previous
//
#include <hip/hip_runtime.h>
#include <hip/hip_bf16.h>

#define NGROUP 8
#define NB     32
#define TLEN   2048
#define LLEN   128
#define TDIM   768
#define VDIM   1024
#define ADIM   1024
#define DH     128          // ADIM / NGROUP
#define TT     64           // T tile
#define NTILE  (TLEN / TT)  // 32
#define ESTR   68           // padded stride for E [128][68] (rows 16B-aligned)

// LDS layout (bytes):
//   qT   ushort[128][128]   @0        32768   (qT[dd][l], bf16)
//   vvS  ushort[128][128]   @32768    32768   (vv[l][dim], bf16)
//   kT   ushort[128][64]    @65536    16384   (kT[dd][tt], bf16)
//   vtS  ushort[64][128]    @81920    16384   (vt[tt][dim], bf16)
//   E    float[128][68]     @98304    34816   [overlaid: Xst float[16][132] = 8448]
//   scale_col float[64]     @133120   256
//   s_row     float[128]    @133376   512
#define SMEM_BYTES 133888

__device__ __forceinline__ unsigned short f2bf(float f) {
    unsigned int u = __float_as_uint(f);
    u = (u + 0x7fffu + ((u >> 16) & 1u)) >> 16;   // round-to-nearest-even
    return (unsigned short)u;
}
__device__ __forceinline__ float bfbits(unsigned short h) {
    return __uint_as_float(((unsigned int)h) << 16);
}
__device__ __forceinline__ void unpk(unsigned int u, float& lo, float& hi) {
    lo = __uint_as_float(u << 16);
    hi = __uint_as_float(u & 0xffff0000u);
}

extern "C" __global__ __launch_bounds__(1024)
void attn_fused(const float* __restrict__ videofea,  // [b][vd][T]
                const float* __restrict__ textfea,   // [b][L][td]
                const int*   __restrict__ mask,      // [b][T][L]
                const float* __restrict__ Wq,  const float* __restrict__ bq,
                const float* __restrict__ Wk,  const float* __restrict__ bk,
                const float* __restrict__ Wvv, const float* __restrict__ bvv,
                const float* __restrict__ Wvt, const float* __restrict__ bvt,
                float* __restrict__ out)             // out_v [32][1024][2048] ++ out_t [32][128][1024]
{
    extern __shared__ char smem[];
    unsigned short* qT  = (unsigned short*)(smem);
    unsigned short* vvS = (unsigned short*)(smem + 32768);
    unsigned short* kT  = (unsigned short*)(smem + 65536);
    unsigned short* vtS = (unsigned short*)(smem + 81920);
    float* E    = (float*)(smem + 98304);
    float* Xst  = (float*)(smem + 98304);   // overlay, used only in Phase 0
    float* scale_col = (float*)(smem + 133120);
    float* s_row     = (float*)(smem + 133376);

    const int tid = threadIdx.x;
    const int g = blockIdx.x, b = blockIdx.y;
    const int gd0 = g * DH;

    const float* Vb   = videofea + (size_t)b * VDIM * TLEN;
    const float* Xb   = textfea  + (size_t)b * LLEN * TDIM;
    const int*   Mb   = mask     + (size_t)b * TLEN * LLEN;
    float* outv = out;
    float* outt = out + (size_t)NB * ADIM * TLEN;

    // ================= Phase 0: q and vv projections (one-time) =================
    {
        const int tx = tid & 31, ty = tid >> 5;     // dim0 = tx*4, l0 = ty*4
        const int dim0 = tx * 4, l0 = ty * 4;
        float aq[4][4], av[4][4];
        #pragma unroll
        for (int i = 0; i < 4; ++i)
            #pragma unroll
            for (int j = 0; j < 4; ++j) { aq[i][j] = 0.f; av[i][j] = 0.f; }

        for (int c0 = 0; c0 < TDIM; c0 += 16) {
            __syncthreads();  // protect Xst reuse
            #pragma unroll
            for (int r = 0; r < 2; ++r) {
                int idx = r * 1024 + tid;            // 0..2047
                int l = idx >> 4, kk = idx & 15;
                Xst[kk * 132 + l] = Xb[l * TDIM + c0 + kk];
            }
            __syncthreads();
            #pragma unroll 4
            for (int kk = 0; kk < 16; ++kk) {
                const float4 x4 = *(const float4*)&Xst[kk * 132 + l0];
                const float4 wq = *(const float4*)&Wq [(size_t)(c0 + kk) * ADIM + gd0 + dim0];
                const float4 wv = *(const float4*)&Wvv[(size_t)(c0 + kk) * ADIM + gd0 + dim0];
                const float xs[4] = {x4.x, x4.y, x4.z, x4.w};
                const float qs[4] = {wq.x, wq.y, wq.z, wq.w};
                const float vs[4] = {wv.x, wv.y, wv.z, wv.w};
                #pragma unroll
                for (int i = 0; i < 4; ++i)
                    #pragma unroll
                    for (int j = 0; j < 4; ++j) {
                        aq[i][j] += xs[i] * qs[j];
                        av[i][j] += xs[i] * vs[j];
                    }
            }
        }
        const float4 bq4 = *(const float4*)&bq [gd0 + dim0];
        const float4 bv4 = *(const float4*)&bvv[gd0 + dim0];
        const float bqs[4] = {bq4.x, bq4.y, bq4.z, bq4.w};
        const float bvs[4] = {bv4.x, bv4.y, bv4.z, bv4.w};
        #pragma unroll
        for (int j = 0; j < 4; ++j) {   // qT[dim][l]: pack 4 l's
            ushort4 p;
            p.x = f2bf(aq[0][j] + bqs[j]); p.y = f2bf(aq[1][j] + bqs[j]);
            p.z = f2bf(aq[2][j] + bqs[j]); p.w = f2bf(aq[3][j] + bqs[j]);
            *(ushort4*)&qT[(dim0 + j) * LLEN + l0] = p;
        }
        #pragma unroll
        for (int i = 0; i < 4; ++i) {   // vvS[l][dim]: pack 4 dims
            ushort4 p;
            p.x = f2bf(av[i][0] + bvs[0]); p.y = f2bf(av[i][1] + bvs[1]);
            p.z = f2bf(av[i][2] + bvs[2]); p.w = f2bf(av[i][3] + bvs[3]);
            *(ushort4*)&vvS[(l0 + i) * DH + dim0] = p;
        }
    }
    if (tid < 128) s_row[tid] = 0.f;

    // out_t accumulator lives in threads 256..767 (waves 4..11): [l(4)][dim(8)]
    float acct[4][8];
    #pragma unroll
    for (int i = 0; i < 4; ++i)
        #pragma unroll
        for (int j = 0; j < 8; ++j) acct[i][j] = 0.f;
    __syncthreads();

    // ================= main loop over T tiles =================
    for (int it = 0; it < NTILE; ++it) {
        const int t0 = it * TT;

        // ---- Phase A: k/vt projection for this tile (all 1024 threads) ----
        {
            const int mat = tid >> 9;                // 0: k, 1: vt
            const int u = tid & 511;
            const int tx = u & 31, ty = u >> 5;      // dim0 = tx*4, tt0 = ty*4
            const int dim0 = tx * 4, tt0 = ty * 4;
            const float* W = mat ? Wvt : Wk;
            float acc[4][4];
            #pragma unroll
            for (int i = 0; i < 4; ++i)
                #pragma unroll
                for (int j = 0; j < 4; ++j) acc[i][j] = 0.f;

            const float* vp = Vb + t0 + tt0;
            const float* wp = W + gd0 + dim0;
            #pragma unroll 4
            for (int c = 0; c < VDIM; ++c) {
                const float4 v4 = *(const float4*)vp;
                const float4 w4 = *(const float4*)wp;
                vp += TLEN; wp += ADIM;
                const float v[4] = {v4.x, v4.y, v4.z, v4.w};
                const float w[4] = {w4.x, w4.y, w4.z, w4.w};
                #pragma unroll
                for (int i = 0; i < 4; ++i)
                    #pragma unroll
                    for (int j = 0; j < 4; ++j) acc[i][j] += v[i] * w[j];
            }
            const float4 b4 = *(const float4*)&(mat ? bvt : bk)[gd0 + dim0];
            const float bs[4] = {b4.x, b4.y, b4.z, b4.w};
            if (mat == 0) {
                #pragma unroll
                for (int j = 0; j < 4; ++j) {        // kT[dim][tt]: pack 4 tt
                    ushort4 p;
                    p.x = f2bf(acc[0][j] + bs[j]); p.y = f2bf(acc[1][j] + bs[j]);
                    p.z = f2bf(acc[2][j] + bs[j]); p.w = f2bf(acc[3][j] + bs[j]);
                    *(ushort4*)&kT[(dim0 + j) * TT + tt0] = p;
                }
            } else {
                #pragma unroll
                for (int i = 0; i < 4; ++i) {        // vtS[tt][dim]: pack 4 dims
                    ushort4 p;
                    p.x = f2bf(acc[i][0] + bs[0]); p.y = f2bf(acc[i][1] + bs[1]);
                    p.z = f2bf(acc[i][2] + bs[2]); p.w = f2bf(acc[i][3] + bs[3]);
                    *(ushort4*)&vtS[(tt0 + i) * DH + dim0] = p;
                }
            }
        }
        __syncthreads();

        // ---- Phase B: S = q·kT, mask, exp -> E (threads 0..511) ----
        if (tid < 512) {
            const int tx = tid & 15, ty = tid >> 4;  // tt0 = tx*4, l0 = ty*4
            const int tt0 = tx * 4, l0 = ty * 4;
            float s[4][4];                           // [l][t]
            #pragma unroll
            for (int i = 0; i < 4; ++i)
                #pragma unroll
                for (int j = 0; j < 4; ++j) s[i][j] = 0.f;

            #pragma unroll 2
            for (int dd = 0; dd < DH; ++dd) {
                ushort4 qr = *(const ushort4*)&qT[dd * LLEN + l0];
                ushort4 kr = *(const ushort4*)&kT[dd * TT + tt0];
                float qf[4] = {bfbits(qr.x), bfbits(qr.y), bfbits(qr.z), bfbits(qr.w)};
                float kf[4] = {bfbits(kr.x), bfbits(kr.y), bfbits(kr.z), bfbits(kr.w)};
                #pragma unroll
                for (int i = 0; i < 4; ++i)
                    #pragma unroll
                    for (int j = 0; j < 4; ++j) s[i][j] += qf[i] * kf[j];
            }
            float e[4][4];
            #pragma unroll
            for (int j = 0; j < 4; ++j) {
                const int4 m4 = *(const int4*)&Mb[(size_t)(t0 + tt0 + j) * LLEN + l0];
                const int mm[4] = {m4.x, m4.y, m4.z, m4.w};
                #pragma unroll
                for (int i = 0; i < 4; ++i)
                    e[i][j] = (mm[i] == 0) ? 0.f : __expf(s[i][j]);
            }
            #pragma unroll
            for (int i = 0; i < 4; ++i) {
                float4 e4 = {e[i][0], e[i][1], e[i][2], e[i][3]};
                *(float4*)&E[(l0 + i) * ESTR + tt0] = e4;
            }
        }
        __syncthreads();

        // ---- Phase C: column sums (softmax over L) + row sum accumulation ----
        if (tid < 512) {
            const int col = tid >> 3, sub = tid & 7;
            float cs = 0.f;
            #pragma unroll 4
            for (int l = sub * 16; l < sub * 16 + 16; ++l) cs += E[l * ESTR + col];
            cs += __shfl_xor(cs, 1); cs += __shfl_xor(cs, 2); cs += __shfl_xor(cs, 4);
            if (sub == 0) scale_col[col] = 1.0f / (32.0f * fmaxf(cs, 1e-30f));
        } else {
            const int u = tid - 512;
            const int r = u >> 2, sub = u & 3;
            float rs = 0.f;
            #pragma unroll 4
            for (int tt = sub * 16; tt < sub * 16 + 16; ++tt) rs += E[r * ESTR + tt];
            rs += __shfl_xor(rs, 1); rs += __shfl_xor(rs, 2);
            if (sub == 0) s_row[r] += rs;
        }
        __syncthreads();

        // ---- Phase D (waves 0-3): out_v tile = (E^T · vv) * scale_col
        //      Phase E (waves 4-11): acct += E · vt       (concurrent, read-only LDS)
        if (tid < 256) {
            const int tx = tid & 15, ty = tid >> 4;  // tt0 = tx*4, dim0 = ty*8
            const int tt0 = tx * 4, dim0 = ty * 8;
            float acc[8][4];
            #pragma unroll
            for (int j = 0; j < 8; ++j)
                #pragma unroll
                for (int i = 0; i < 4; ++i) acc[j][i] = 0.f;

            #pragma unroll 2
            for (int l = 0; l < LLEN; ++l) {
                const float4 e4 = *(const float4*)&E[l * ESTR + tt0];
                const float es[4] = {e4.x, e4.y, e4.z, e4.w};
                const uint4 vr = *(const uint4*)&vvS[l * DH + dim0];
                float v8[8];
                unpk(vr.x, v8[0], v8[1]); unpk(vr.y, v8[2], v8[3]);
                unpk(vr.z, v8[4], v8[5]); unpk(vr.w, v8[6], v8[7]);
                #pragma unroll
                for (int j = 0; j < 8; ++j)
                    #pragma unroll
                    for (int i = 0; i < 4; ++i) acc[j][i] += v8[j] * es[i];
            }
            const float4 sc4 = *(const float4*)&scale_col[tt0];
            const float sc[4] = {sc4.x, sc4.y, sc4.z, sc4.w};
            #pragma unroll
            for (int j = 0; j < 8; ++j) {
                float4 o = {acc[j][0] * sc[0], acc[j][1] * sc[1], acc[j][2] * sc[2], acc[j][3] * sc[3]};
                *(float4*)&outv[((size_t)b * ADIM + gd0 + dim0 + j) * TLEN + t0 + tt0] = o;
            }
        } else if (tid < 768) {
            const int u = tid - 256;
            const int tx = u & 15, ty = u >> 4;      // dim0 = tx*8, l0 = ty*4
            const int dim0 = tx * 8, l0 = ty * 4;
            for (int tt4 = 0; tt4 < TT; tt4 += 4) {
                const float4 e0 = *(const float4*)&E[(l0 + 0) * ESTR + tt4];
                const float4 e1 = *(const float4*)&E[(l0 + 1) * ESTR + tt4];
                const float4 e2 = *(const float4*)&E[(l0 + 2) * ESTR + tt4];
                const float4 e3 = *(const float4*)&E[(l0 + 3) * ESTR + tt4];
                const float er[4][4] = {{e0.x, e0.y, e0.z, e0.w}, {e1.x, e1.y, e1.z, e1.w},
                                        {e2.x, e2.y, e2.z, e2.w}, {e3.x, e3.y, e3.z, e3.w}};
                #pragma unroll
                for (int s = 0; s < 4; ++s) {
                    const uint4 vr = *(const uint4*)&vtS[(tt4 + s) * DH + dim0];
                    float v8[8];
                    unpk(vr.x, v8[0], v8[1]); unpk(vr.y, v8[2], v8[3]);
                    unpk(vr.z, v8[4], v8[5]); unpk(vr.w, v8[6], v8[7]);
                    #pragma unroll
                    for (int i = 0; i < 4; ++i)
                        #pragma unroll
                        for (int j = 0; j < 8; ++j) acct[i][j] += er[i][s] * v8[j];
                }
            }
        }
        __syncthreads();  // protect kT/vtS/E before next tile's Phase A/B
    }

    // ================= epilogue: out_t = acct / (32 * s_row) =================
    if (tid >= 256 && tid < 768) {
        const int u = tid - 256;
        const int tx = u & 15, ty = u >> 4;
        const int dim0 = tx * 8, l0 = ty * 4;
        #pragma unroll
        for (int i = 0; i < 4; ++i) {
            float inv = 1.0f / (32.0f * fmaxf(s_row[l0 + i], 1e-30f));
            float4 o0 = {acct[i][0] * inv, acct[i][1] * inv, acct[i][2] * inv, acct[i][3] * inv};
            float4 o1 = {acct[i][4] * inv, acct[i][5] * inv, acct[i][6] * inv, acct[i][7] * inv};
            size_t base = (size_t)b * LLEN * ADIM + (size_t)(l0 + i) * ADIM + gd0 + dim0;
            *(float4*)&outt[base]     = o0;
            *(float4*)&outt[base + 4] = o1;
        }
    }
}

extern "C" void kernel_launch(void* const* d_in, const int* in_sizes, int n_in,
                              void* d_out, int out_size, void* d_ws, size_t ws_size,
                              hipStream_t stream) {
    const float* videofea = (const float*)d_in[0];
    const float* textfea  = (const float*)d_in[1];
    const int*   mask     = (const int*)d_in[2];
    const float* Wq  = (const float*)d_in[3];
    const float* bq  = (const float*)d_in[4];
    const float* Wk  = (const float*)d_in[5];
    const float* bk  = (const float*)d_in[6];
    const float* Wvv = (const float*)d_in[7];
    const float* bvv = (const float*)d_in[8];
    const float* Wvt = (const float*)d_in[9];
    const float* bvt = (const float*)d_in[10];
    float* out = (float*)d_out;

    hipFuncSetAttribute((const void*)attn_fused,
                        hipFuncAttributeMaxDynamicSharedMemorySize, SMEM_BYTES);
    dim3 grid(NGROUP, NB);
    attn_fused<<<grid, 1024, SMEM_BYTES, stream>>>(
        videofea, textfea, mask, Wq, bq, Wk, bk, Wvv, bvv, Wvt, bvt, out);
}